// Round 4
// baseline (59.603 us; speedup 1.0000x reference)
//
#include <hip/hip_runtime.h>
#include <math.h>

#define B_DIM 4096
#define L_DIM 512
#define N_DIM 1024

// -half*log(2): exact value of each term once P has fully underflowed to zero.
#define NEG_HALF_LOG2 (-0.34657359027997264f)

// ---------------------------------------------------------------------------
// Kernel A: transpose eps (2, N, L) -> epsT (L, 2, N) so per-step reads are
// contiguous in n. Standard 32x32 LDS tile transpose, both sides coalesced.
// ---------------------------------------------------------------------------
__global__ void transpose_eps(const float* __restrict__ eps,
                              float* __restrict__ epsT) {
    __shared__ float tile[32][33];
    const int s  = blockIdx.z;
    const int i0 = blockIdx.x * 32;   // i tile base (L dim)
    const int n0 = blockIdx.y * 32;   // n tile base (N dim)
    const int tx = threadIdx.x;       // 0..31
    const int ty = threadIdx.y;       // 0..7
#pragma unroll
    for (int k = 0; k < 32; k += 8) {
        tile[ty + k][tx] =
            eps[((size_t)s * N_DIM + (size_t)(n0 + ty + k)) * L_DIM + (i0 + tx)];
    }
    __syncthreads();
#pragma unroll
    for (int k = 0; k < 32; k += 8) {
        epsT[(size_t)(i0 + ty + k) * (2 * N_DIM) + (size_t)s * N_DIM + (n0 + tx)] =
            tile[tx][ty + k];
    }
}

// ---------------------------------------------------------------------------
// DPP wave-64 sum (ctrl must be a compile-time constant -> template arg).
// After the sequence lane 63 holds the full 64-lane sum. All VALU-pipe.
// ---------------------------------------------------------------------------
template <int CTRL>
__device__ __forceinline__ float dpp_add(float x) {
    int v = __builtin_amdgcn_update_dpp(0, __float_as_int(x), CTRL, 0xf, 0xf, true);
    return x + __int_as_float(v);
}
__device__ __forceinline__ float wave_sum63(float x) {
    x = dpp_add<0x111>(x);  // row_shr:1
    x = dpp_add<0x112>(x);  // row_shr:2
    x = dpp_add<0x114>(x);  // row_shr:4
    x = dpp_add<0x118>(x);  // row_shr:8
    x = dpp_add<0x142>(x);  // row_bcast:15
    x = dpp_add<0x143>(x);  // row_bcast:31
    return x;
}
__device__ __forceinline__ float read63(float x) {
    return __int_as_float(__builtin_amdgcn_readlane(__float_as_int(x), 63));
}

__device__ __forceinline__ void dot4(const float4 e, const float4 p, float& a) {
    a = fmaf(e.x, p.x, a); a = fmaf(e.y, p.y, a);
    a = fmaf(e.z, p.z, a); a = fmaf(e.w, p.w, a);
}

// ---------------------------------------------------------------------------
// Kernel B: one 64-lane wave per row b. Lane owns 16 n's (4 x float4) of the
// running product P in VGPRs. Branch-free body, 8-step unrolled, depth-2
// software pipeline: step k+1's eps slices are prefetched into the other half
// of a double buffer while step k computes. Early-exit vote every 8 steps
// (overshoot is exact: post-underflow terms are exactly -1/2*log2).
// ---------------------------------------------------------------------------
template <bool USE_T>
__global__ __launch_bounds__(512, 4) void arqgps_main(
    const int* __restrict__ indices,
    const float* __restrict__ eps,    // original (2,N,L) layout (fallback)
    const float* __restrict__ epsT,   // transposed (L,2,N) layout
    float* __restrict__ out)
{
    const int lane  = threadIdx.x & 63;
    const int wave  = __builtin_amdgcn_readfirstlane((int)(threadIdx.x >> 6));
    const int b     = blockIdx.x * 8 + wave;
    const int lane4 = lane * 4;
    const int* idx_row = indices + (size_t)b * L_DIM;

    float4 P[4];
#pragma unroll
    for (int c = 0; c < 4; ++c) P[c] = make_float4(1.f, 1.f, 1.f, 1.f);
    float acc = 0.0f;

    // Double-buffered eps slices: E*[buf][chunk]. buf index is always a
    // compile-time constant (k&1 inside a fully unrolled loop).
    float4 E0[2][4], E1[2][4];

    // Prime: load step i=0 into buffer 0.
    {
        const float* p0 = epsT;            // i = 0
        const float* p1 = epsT + N_DIM;
        if (USE_T) {
#pragma unroll
            for (int c = 0; c < 4; ++c) {
                E0[0][c] = *(const float4*)(p0 + c * 256 + lane4);
                E1[0][c] = *(const float4*)(p1 + c * 256 + lane4);
            }
        } else {
#pragma unroll
            for (int c = 0; c < 4; ++c) {
                const int n = c * 256 + lane4;
                float t0[4], t1[4];
#pragma unroll
                for (int j = 0; j < 4; ++j) {
                    t0[j] = eps[(size_t)(n + j) * L_DIM];
                    t1[j] = eps[((size_t)N_DIM + n + j) * L_DIM];
                }
                E0[0][c] = make_float4(t0[0], t0[1], t0[2], t0[3]);
                E1[0][c] = make_float4(t1[0], t1[1], t1[2], t1[3]);
            }
        }
    }

    for (int i0 = 0; i0 < L_DIM; i0 += 8) {
        // 8 indices for this chunk via two uniform 16B loads.
        const int4 sA = *(const int4*)(idx_row + i0);
        const int4 sB = *(const int4*)(idx_row + i0 + 4);
#pragma unroll
        for (int k = 0; k < 8; ++k) {
            const int cur = k & 1;
            const int nxt = cur ^ 1;

            // Prefetch step i0+k+1 (clamped at the last slice; the clamped
            // duplicate is never consumed).
            {
                int inext = i0 + k + 1;
                inext = (inext < L_DIM) ? inext : (L_DIM - 1);
                const float* p0 = epsT + (size_t)inext * (2 * N_DIM);
                const float* p1 = p0 + N_DIM;
                if (USE_T) {
#pragma unroll
                    for (int c = 0; c < 4; ++c) {
                        E0[nxt][c] = *(const float4*)(p0 + c * 256 + lane4);
                        E1[nxt][c] = *(const float4*)(p1 + c * 256 + lane4);
                    }
                } else {
#pragma unroll
                    for (int c = 0; c < 4; ++c) {
                        const int n = c * 256 + lane4;
                        float t0[4], t1[4];
#pragma unroll
                        for (int j = 0; j < 4; ++j) {
                            t0[j] = eps[(size_t)(n + j) * L_DIM + inext];
                            t1[j] = eps[((size_t)N_DIM + n + j) * L_DIM + inext];
                        }
                        E0[nxt][c] = make_float4(t0[0], t0[1], t0[2], t0[3]);
                        E1[nxt][c] = make_float4(t1[0], t1[1], t1[2], t1[3]);
                    }
                }
            }

            // Two dot products against P, 4 independent accumulators each.
            float x00 = 0.f, x01 = 0.f, x02 = 0.f, x03 = 0.f;
            float x10 = 0.f, x11 = 0.f, x12 = 0.f, x13 = 0.f;
            dot4(E0[cur][0], P[0], x00); dot4(E0[cur][1], P[1], x01);
            dot4(E0[cur][2], P[2], x02); dot4(E0[cur][3], P[3], x03);
            dot4(E1[cur][0], P[0], x10); dot4(E1[cur][1], P[1], x11);
            dot4(E1[cur][2], P[2], x12); dot4(E1[cur][3], P[3], x13);
            const float X0 = read63(wave_sum63((x00 + x01) + (x02 + x03)));
            const float X1 = read63(wave_sum63((x10 + x11) + (x12 + x13)));

            const int kidx = (k == 0) ? sA.x : (k == 1) ? sA.y
                           : (k == 2) ? sA.z : (k == 3) ? sA.w
                           : (k == 4) ? sB.x : (k == 5) ? sB.y
                           : (k == 6) ? sB.z : sB.w;
            const int s_i = __builtin_amdgcn_readfirstlane(kidx);

            // acc += picked - 1/2 * logsumexp(2*X0, 2*X1)   (uniform math)
            const float xs = s_i ? X1 : X0;
            const float m  = fmaxf(X0, X1);
            const float d  = fabsf(X0 - X1);
            acc += (xs - m) - 0.5f * __logf(1.0f + __expf(-2.0f * d));

            // Branch-free P update (cndmask select on the uniform s_i).
#pragma unroll
            for (int c = 0; c < 4; ++c) {
                const float4 e0v = E0[cur][c];
                const float4 e1v = E1[cur][c];
                P[c].x *= s_i ? e1v.x : e0v.x;
                P[c].y *= s_i ? e1v.y : e0v.y;
                P[c].z *= s_i ? e1v.z : e0v.z;
                P[c].w *= s_i ? e1v.w : e0v.w;
            }
        }

        // All-|P|-zero vote once per 8 steps.
        float mx = 0.f;
#pragma unroll
        for (int c = 0; c < 4; ++c) {
            mx = fmaxf(mx, fmaxf(fmaxf(fabsf(P[c].x), fabsf(P[c].y)),
                                 fmaxf(fabsf(P[c].z), fabsf(P[c].w))));
        }
        if (!__any(mx > 0.0f)) {
            // Every remaining step contributes exactly -1/2*log2.
            acc += (float)(L_DIM - 8 - i0) * NEG_HALF_LOG2;
            break;
        }
    }

    if (lane == 0) out[b] = acc;
}

extern "C" void kernel_launch(void* const* d_in, const int* in_sizes, int n_in,
                              void* d_out, int out_size, void* d_ws, size_t ws_size,
                              hipStream_t stream) {
    const int*   indices = (const int*)d_in[0];
    const float* eps     = (const float*)d_in[1];
    float*       out     = (float*)d_out;

    const size_t need = (size_t)2 * N_DIM * L_DIM * sizeof(float);  // 4 MB
    if (ws_size >= need) {
        float* epsT = (float*)d_ws;
        dim3 tgrid(L_DIM / 32, N_DIM / 32, 2);
        transpose_eps<<<tgrid, dim3(32, 8), 0, stream>>>(eps, epsT);
        arqgps_main<true><<<B_DIM / 8, 512, 0, stream>>>(indices, eps, epsT, out);
    } else {
        arqgps_main<false><<<B_DIM / 8, 512, 0, stream>>>(indices, eps, nullptr, out);
    }
}

// Round 6
// 56.159 us; speedup vs baseline: 1.0613x; 1.0613x over previous
//
#include <hip/hip_runtime.h>
#include <math.h>

#define B_DIM 4096
#define L_DIM 512
#define N_DIM 1024

// -half*log(2): exact value of each term once P has fully underflowed to zero.
#define NEG_HALF_LOG2 (-0.34657359027997264f)

typedef float f32x2 __attribute__((ext_vector_type(2)));
typedef float f32x4 __attribute__((ext_vector_type(4)));
#define VLO(v) __builtin_shufflevector(v, v, 0, 1)
#define VHI(v) __builtin_shufflevector(v, v, 2, 3)

// ---------------------------------------------------------------------------
// Packed fp32 ops (VOP3P). The HIP compiler never auto-emits these; they run
// at 2x the scalar v_fma_f32 rate (the 157.3 TF FP32 spec path on CDNA4).
// ---------------------------------------------------------------------------
__device__ __forceinline__ f32x2 pk_fma(f32x2 a, f32x2 b, f32x2 c) {
    f32x2 d;
    asm("v_pk_fma_f32 %0, %1, %2, %3" : "=v"(d) : "v"(a), "v"(b), "v"(c));
    return d;
}
__device__ __forceinline__ f32x2 pk_mul(f32x2 a, f32x2 b) {
    f32x2 d;
    asm("v_pk_mul_f32 %0, %1, %2" : "=v"(d) : "v"(a), "v"(b));
    return d;
}
__device__ __forceinline__ f32x2 pk_add(f32x2 a, f32x2 b) {
    f32x2 d;
    asm("v_pk_add_f32 %0, %1, %2" : "=v"(d) : "v"(a), "v"(b));
    return d;
}

// ---------------------------------------------------------------------------
// Kernel A: transpose eps (2, N, L) -> epsT (L, 2, N).
// ---------------------------------------------------------------------------
__global__ void transpose_eps(const float* __restrict__ eps,
                              float* __restrict__ epsT) {
    __shared__ float tile[32][33];
    const int s  = blockIdx.z;
    const int i0 = blockIdx.x * 32;
    const int n0 = blockIdx.y * 32;
    const int tx = threadIdx.x;
    const int ty = threadIdx.y;
#pragma unroll
    for (int k = 0; k < 32; k += 8) {
        tile[ty + k][tx] =
            eps[((size_t)s * N_DIM + (size_t)(n0 + ty + k)) * L_DIM + (i0 + tx)];
    }
    __syncthreads();
#pragma unroll
    for (int k = 0; k < 32; k += 8) {
        epsT[(size_t)(i0 + ty + k) * (2 * N_DIM) + (size_t)s * N_DIM + (n0 + tx)] =
            tile[tx][ty + k];
    }
}

// ---------------------------------------------------------------------------
// DPP wave-64 sum; lane 63 ends with the full sum. All VALU-pipe.
// ---------------------------------------------------------------------------
template <int CTRL>
__device__ __forceinline__ float dpp_add(float x) {
    int v = __builtin_amdgcn_update_dpp(0, __float_as_int(x), CTRL, 0xf, 0xf, true);
    return x + __int_as_float(v);
}
__device__ __forceinline__ float wave_sum63(float x) {
    x = dpp_add<0x111>(x);  // row_shr:1
    x = dpp_add<0x112>(x);  // row_shr:2
    x = dpp_add<0x114>(x);  // row_shr:4
    x = dpp_add<0x118>(x);  // row_shr:8
    x = dpp_add<0x142>(x);  // row_bcast:15
    x = dpp_add<0x143>(x);  // row_bcast:31
    return x;
}
__device__ __forceinline__ float read63(float x) {
    return __int_as_float(__builtin_amdgcn_readlane(__float_as_int(x), 63));
}

// ---------------------------------------------------------------------------
// Kernel B: one wave per row b. Lane owns 16 n's of P as 8 packed f32x2.
// Per step: 8x float4 eps loads, 16 pk_fma (both dots), DPP reduce, place the
// broadcast sums into lane k of two collector regs via cndmask, 8 pk_mul
// P-update under a uniform scalar branch. Tail (logsumexp) is computed once
// per 8-step chunk, vectorized across lanes 0..7. Early-exit vote every 8
// steps (exact: post-underflow terms are exactly -1/2*log2).
// ---------------------------------------------------------------------------
template <bool USE_T>
__global__ __launch_bounds__(512, 4) void arqgps_main(
    const int* __restrict__ indices,
    const float* __restrict__ eps,    // original (2,N,L) layout (fallback)
    const float* __restrict__ epsT,   // transposed (L,2,N) layout
    float* __restrict__ out)
{
    const int lane  = threadIdx.x & 63;
    const int wave  = __builtin_amdgcn_readfirstlane((int)(threadIdx.x >> 6));
    const int b     = blockIdx.x * 8 + wave;
    const int lane4 = lane * 4;
    const int* idx_row = indices + (size_t)b * L_DIM;

    f32x2 P[8];
#pragma unroll
    for (int c = 0; c < 8; ++c) P[c] = (f32x2){1.0f, 1.0f};

    float vacc  = 0.0f;   // per-lane batched-tail accumulator (lanes 0..7 live)
    float uacc  = 0.0f;   // uniform early-exit remainder
    float collA = 0.0f, collB = 0.0f;

    for (int i0 = 0; i0 < L_DIM; i0 += 8) {
        const int4 sA = *(const int4*)(idx_row + i0);
        const int4 sB = *(const int4*)(idx_row + i0 + 4);
        int smask = 0;
#pragma unroll
        for (int k = 0; k < 8; ++k) {
            const int i = i0 + k;
            f32x4 e0q[4], e1q[4];
            if (USE_T) {
                const float* e = epsT + (size_t)i * (2 * N_DIM);
#pragma unroll
                for (int c = 0; c < 4; ++c) {
                    e0q[c] = *(const f32x4*)(e + c * 256 + lane4);
                    e1q[c] = *(const f32x4*)(e + N_DIM + c * 256 + lane4);
                }
            } else {
#pragma unroll
                for (int c = 0; c < 4; ++c) {
                    const int n = c * 256 + lane4;
                    f32x4 t0, t1;
#pragma unroll
                    for (int j = 0; j < 4; ++j) {
                        t0[j] = eps[(size_t)(n + j) * L_DIM + i];
                        t1[j] = eps[((size_t)N_DIM + n + j) * L_DIM + i];
                    }
                    e0q[c] = t0; e1q[c] = t1;
                }
            }

            // Both dots, packed: 16 pk_fma, 2 accumulators each for ILP.
            f32x2 a00 = {0.f, 0.f}, a01 = {0.f, 0.f};
            f32x2 a10 = {0.f, 0.f}, a11 = {0.f, 0.f};
#pragma unroll
            for (int c = 0; c < 4; ++c) {
                a00 = pk_fma(VLO(e0q[c]), P[2 * c],     a00);
                a01 = pk_fma(VHI(e0q[c]), P[2 * c + 1], a01);
                a10 = pk_fma(VLO(e1q[c]), P[2 * c],     a10);
                a11 = pk_fma(VHI(e1q[c]), P[2 * c + 1], a11);
            }
            const f32x2 s0p = pk_add(a00, a01);
            const f32x2 s1p = pk_add(a10, a11);
            const float X0u = read63(wave_sum63(s0p.x + s0p.y)); // uniform
            const float X1u = read63(wave_sum63(s1p.x + s1p.y)); // uniform

            // Place this step's sums into lane k of the collectors.
            const bool isk = (lane == k);
            collA = isk ? X0u : collA;
            collB = isk ? X1u : collB;

            const int kidx = (k == 0) ? sA.x : (k == 1) ? sA.y
                           : (k == 2) ? sA.z : (k == 3) ? sA.w
                           : (k == 4) ? sB.x : (k == 5) ? sB.y
                           : (k == 6) ? sB.z : sB.w;
            const int s_i = __builtin_amdgcn_readfirstlane(kidx);
            smask |= (s_i << k);

            // P update: 8 pk_mul under a wave-uniform scalar branch.
            if (s_i) {
#pragma unroll
                for (int c = 0; c < 4; ++c) {
                    P[2 * c]     = pk_mul(P[2 * c],     VLO(e1q[c]));
                    P[2 * c + 1] = pk_mul(P[2 * c + 1], VHI(e1q[c]));
                }
            } else {
#pragma unroll
                for (int c = 0; c < 4; ++c) {
                    P[2 * c]     = pk_mul(P[2 * c],     VLO(e0q[c]));
                    P[2 * c + 1] = pk_mul(P[2 * c + 1], VHI(e0q[c]));
                }
            }
        }

        // Batched tail: lane k handles step i0+k (k = 0..7).
        {
            const float Av = collA, Bv = collB;
            const int   sb = (smask >> lane) & 1;
            const float xs = sb ? Bv : Av;
            const float m  = fmaxf(Av, Bv);
            const float d  = fabsf(Av - Bv);
            const float c  = (xs - m) - 0.5f * __logf(1.0f + __expf(-2.0f * d));
            vacc += (lane < 8) ? c : 0.0f;
        }

        // All-|P|-zero vote once per 8 steps.
        float mx = 0.f;
#pragma unroll
        for (int c = 0; c < 8; ++c) {
            mx = fmaxf(mx, fmaxf(fabsf(P[c].x), fabsf(P[c].y)));
        }
        if (!__any(mx > 0.0f)) {
            uacc = (float)(L_DIM - 8 - i0) * NEG_HALF_LOG2;
            break;
        }
    }

    const float tot = read63(wave_sum63(vacc));
    if (lane == 0) out[b] = tot + uacc;
}

extern "C" void kernel_launch(void* const* d_in, const int* in_sizes, int n_in,
                              void* d_out, int out_size, void* d_ws, size_t ws_size,
                              hipStream_t stream) {
    const int*   indices = (const int*)d_in[0];
    const float* eps     = (const float*)d_in[1];
    float*       out     = (float*)d_out;

    const size_t need = (size_t)2 * N_DIM * L_DIM * sizeof(float);  // 4 MB
    if (ws_size >= need) {
        float* epsT = (float*)d_ws;
        dim3 tgrid(L_DIM / 32, N_DIM / 32, 2);
        transpose_eps<<<tgrid, dim3(32, 8), 0, stream>>>(eps, epsT);
        arqgps_main<true><<<B_DIM / 8, 512, 0, stream>>>(indices, eps, epsT, out);
    } else {
        arqgps_main<false><<<B_DIM / 8, 512, 0, stream>>>(indices, eps, nullptr, out);
    }
}

// Round 7
// 40.869 us; speedup vs baseline: 1.4584x; 1.3741x over previous
//
#include <hip/hip_runtime.h>
#include <math.h>

#define B_DIM 4096
#define L_DIM 512
#define N_DIM 1024

// -half*log(2): exact value of each term once P has fully underflowed to zero.
#define NEG_HALF_LOG2 (-0.34657359027997264f)

typedef float f32x2 __attribute__((ext_vector_type(2)));
typedef float f32x4 __attribute__((ext_vector_type(4)));
#define VLO(v) __builtin_shufflevector(v, v, 0, 1)
#define VHI(v) __builtin_shufflevector(v, v, 2, 3)

// ---------------------------------------------------------------------------
// Packed fp32 ops (VOP3P), 2x the scalar v_fma_f32 rate on CDNA4.
// ---------------------------------------------------------------------------
__device__ __forceinline__ f32x2 pk_fma(f32x2 a, f32x2 b, f32x2 c) {
    f32x2 d;
    asm("v_pk_fma_f32 %0, %1, %2, %3" : "=v"(d) : "v"(a), "v"(b), "v"(c));
    return d;
}
__device__ __forceinline__ f32x2 pk_mul(f32x2 a, f32x2 b) {
    f32x2 d;
    asm("v_pk_mul_f32 %0, %1, %2" : "=v"(d) : "v"(a), "v"(b));
    return d;
}
__device__ __forceinline__ f32x2 pk_add(f32x2 a, f32x2 b) {
    f32x2 d;
    asm("v_pk_add_f32 %0, %1, %2" : "=v"(d) : "v"(a), "v"(b));
    return d;
}

// ---------------------------------------------------------------------------
// Kernel A: transpose eps (2, N, L) -> epsT (L, 2, N).
// ---------------------------------------------------------------------------
__global__ void transpose_eps(const float* __restrict__ eps,
                              float* __restrict__ epsT) {
    __shared__ float tile[32][33];
    const int s  = blockIdx.z;
    const int i0 = blockIdx.x * 32;
    const int n0 = blockIdx.y * 32;
    const int tx = threadIdx.x;
    const int ty = threadIdx.y;
#pragma unroll
    for (int k = 0; k < 32; k += 8) {
        tile[ty + k][tx] =
            eps[((size_t)s * N_DIM + (size_t)(n0 + ty + k)) * L_DIM + (i0 + tx)];
    }
    __syncthreads();
#pragma unroll
    for (int k = 0; k < 32; k += 8) {
        epsT[(size_t)(i0 + ty + k) * (2 * N_DIM) + (size_t)s * N_DIM + (n0 + tx)] =
            tile[tx][ty + k];
    }
}

// ---------------------------------------------------------------------------
// DPP wave-64 sum; lane 63 ends with the full sum. All VALU-pipe.
// ---------------------------------------------------------------------------
template <int CTRL>
__device__ __forceinline__ float dpp_add(float x) {
    int v = __builtin_amdgcn_update_dpp(0, __float_as_int(x), CTRL, 0xf, 0xf, true);
    return x + __int_as_float(v);
}
__device__ __forceinline__ float wave_sum63(float x) {
    x = dpp_add<0x111>(x);  // row_shr:1
    x = dpp_add<0x112>(x);  // row_shr:2
    x = dpp_add<0x114>(x);  // row_shr:4
    x = dpp_add<0x118>(x);  // row_shr:8
    x = dpp_add<0x142>(x);  // row_bcast:15
    x = dpp_add<0x143>(x);  // row_bcast:31
    return x;
}
__device__ __forceinline__ float read63(float x) {
    return __int_as_float(__builtin_amdgcn_readlane(__float_as_int(x), 63));
}

// ---------------------------------------------------------------------------
// Kernel B: one wave handles TWO rows (b0, b1) sharing each step's eps slice
// in registers — halves cache traffic per row (we are cache-BW-bound).
// Lane owns 16 n's of each row's running product P as 8 packed f32x2.
// Per step: 8x b128 eps loads, 32 pk_fma (2 rows x 2 dots), 4 DPP reduces,
// place the 4 sums into collector lanes (row0 -> lane k, row1 -> lane 8+k),
// 16 pk_mul P-updates under uniform scalar branches. Batched logsumexp tail
// once per 8-step chunk across lanes 0..15. Joint early-exit vote every 8
// steps (a dead row's term computes to exactly -1/2*log2, so running one row
// past its underflow point is exact).
// ---------------------------------------------------------------------------
template <bool USE_T>
__global__ __launch_bounds__(512, 2) void arqgps_main(
    const int* __restrict__ indices,
    const float* __restrict__ eps,    // original (2,N,L) layout (fallback)
    const float* __restrict__ epsT,   // transposed (L,2,N) layout
    float* __restrict__ out)
{
    const int lane  = threadIdx.x & 63;
    const int wave  = __builtin_amdgcn_readfirstlane((int)(threadIdx.x >> 6));
    const int b0    = (blockIdx.x * 8 + wave) * 2;
    const int b1    = b0 + 1;
    const int lane4 = lane * 4;
    const int* idx0 = indices + (size_t)b0 * L_DIM;
    const int* idx1 = indices + (size_t)b1 * L_DIM;

    f32x2 P0[8], P1[8];
#pragma unroll
    for (int c = 0; c < 8; ++c) {
        P0[c] = (f32x2){1.0f, 1.0f};
        P1[c] = (f32x2){1.0f, 1.0f};
    }

    float vacc = 0.0f;   // batched-tail accumulator (lanes 0..15 live)
    float uacc = 0.0f;   // uniform early-exit remainder (joint for both rows)
    float collA = 0.0f, collB = 0.0f;   // x0 / x1 collectors (both rows)

    for (int i0 = 0; i0 < L_DIM; i0 += 8) {
        const int4 sA0 = *(const int4*)(idx0 + i0);
        const int4 sB0 = *(const int4*)(idx0 + i0 + 4);
        const int4 sA1 = *(const int4*)(idx1 + i0);
        const int4 sB1 = *(const int4*)(idx1 + i0 + 4);
        int smask0 = 0, smask1 = 0;
#pragma unroll
        for (int k = 0; k < 8; ++k) {
            const int i = i0 + k;
            f32x4 e0q[4], e1q[4];
            if (USE_T) {
                const float* e = epsT + (size_t)i * (2 * N_DIM);
#pragma unroll
                for (int c = 0; c < 4; ++c) {
                    e0q[c] = *(const f32x4*)(e + c * 256 + lane4);
                    e1q[c] = *(const f32x4*)(e + N_DIM + c * 256 + lane4);
                }
            } else {
#pragma unroll
                for (int c = 0; c < 4; ++c) {
                    const int n = c * 256 + lane4;
                    f32x4 t0, t1;
#pragma unroll
                    for (int j = 0; j < 4; ++j) {
                        t0[j] = eps[(size_t)(n + j) * L_DIM + i];
                        t1[j] = eps[((size_t)N_DIM + n + j) * L_DIM + i];
                    }
                    e0q[c] = t0; e1q[c] = t1;
                }
            }

            // Row 0 dots.
            f32x2 a00 = {0.f, 0.f}, a01 = {0.f, 0.f};
            f32x2 a10 = {0.f, 0.f}, a11 = {0.f, 0.f};
            // Row 1 dots.
            f32x2 c00 = {0.f, 0.f}, c01 = {0.f, 0.f};
            f32x2 c10 = {0.f, 0.f}, c11 = {0.f, 0.f};
#pragma unroll
            for (int c = 0; c < 4; ++c) {
                const f32x2 lo0 = VLO(e0q[c]), hi0 = VHI(e0q[c]);
                const f32x2 lo1 = VLO(e1q[c]), hi1 = VHI(e1q[c]);
                a00 = pk_fma(lo0, P0[2 * c],     a00);
                a01 = pk_fma(hi0, P0[2 * c + 1], a01);
                a10 = pk_fma(lo1, P0[2 * c],     a10);
                a11 = pk_fma(hi1, P0[2 * c + 1], a11);
                c00 = pk_fma(lo0, P1[2 * c],     c00);
                c01 = pk_fma(hi0, P1[2 * c + 1], c01);
                c10 = pk_fma(lo1, P1[2 * c],     c10);
                c11 = pk_fma(hi1, P1[2 * c + 1], c11);
            }
            const f32x2 r0x0 = pk_add(a00, a01);
            const f32x2 r0x1 = pk_add(a10, a11);
            const f32x2 r1x0 = pk_add(c00, c01);
            const f32x2 r1x1 = pk_add(c10, c11);
            const float X00 = read63(wave_sum63(r0x0.x + r0x0.y)); // row0 x0
            const float X01 = read63(wave_sum63(r0x1.x + r0x1.y)); // row0 x1
            const float X10 = read63(wave_sum63(r1x0.x + r1x0.y)); // row1 x0
            const float X11 = read63(wave_sum63(r1x1.x + r1x1.y)); // row1 x1

            // Collect: row0 step k -> lane k; row1 step k -> lane 8+k.
            const bool isk0 = (lane == k);
            const bool isk1 = (lane == k + 8);
            collA = isk0 ? X00 : (isk1 ? X10 : collA);
            collB = isk0 ? X01 : (isk1 ? X11 : collB);

            const int ki0 = (k == 0) ? sA0.x : (k == 1) ? sA0.y
                          : (k == 2) ? sA0.z : (k == 3) ? sA0.w
                          : (k == 4) ? sB0.x : (k == 5) ? sB0.y
                          : (k == 6) ? sB0.z : sB0.w;
            const int ki1 = (k == 0) ? sA1.x : (k == 1) ? sA1.y
                          : (k == 2) ? sA1.z : (k == 3) ? sA1.w
                          : (k == 4) ? sB1.x : (k == 5) ? sB1.y
                          : (k == 6) ? sB1.z : sB1.w;
            const int s0 = __builtin_amdgcn_readfirstlane(ki0);
            const int s1 = __builtin_amdgcn_readfirstlane(ki1);
            smask0 |= (s0 << k);
            smask1 |= (s1 << k);

            // P updates under wave-uniform scalar branches.
            if (s0) {
#pragma unroll
                for (int c = 0; c < 4; ++c) {
                    P0[2 * c]     = pk_mul(P0[2 * c],     VLO(e1q[c]));
                    P0[2 * c + 1] = pk_mul(P0[2 * c + 1], VHI(e1q[c]));
                }
            } else {
#pragma unroll
                for (int c = 0; c < 4; ++c) {
                    P0[2 * c]     = pk_mul(P0[2 * c],     VLO(e0q[c]));
                    P0[2 * c + 1] = pk_mul(P0[2 * c + 1], VHI(e0q[c]));
                }
            }
            if (s1) {
#pragma unroll
                for (int c = 0; c < 4; ++c) {
                    P1[2 * c]     = pk_mul(P1[2 * c],     VLO(e1q[c]));
                    P1[2 * c + 1] = pk_mul(P1[2 * c + 1], VHI(e1q[c]));
                }
            } else {
#pragma unroll
                for (int c = 0; c < 4; ++c) {
                    P1[2 * c]     = pk_mul(P1[2 * c],     VLO(e0q[c]));
                    P1[2 * c + 1] = pk_mul(P1[2 * c + 1], VHI(e0q[c]));
                }
            }
        }

        // Batched tail: lane k -> row0 step i0+k; lane 8+k -> row1 step i0+k.
        {
            const float Av = collA, Bv = collB;
            const int   kk = lane & 7;
            const int   sm = (lane < 8) ? smask0 : smask1;
            const int   sb = (sm >> kk) & 1;
            const float xs = sb ? Bv : Av;
            const float m  = fmaxf(Av, Bv);
            const float d  = fabsf(Av - Bv);
            const float c  = (xs - m) - 0.5f * __logf(1.0f + __expf(-2.0f * d));
            vacc += (lane < 16) ? c : 0.0f;
        }

        // Joint all-|P|-zero vote once per 8 steps.
        float mx = 0.f;
#pragma unroll
        for (int c = 0; c < 8; ++c) {
            mx = fmaxf(mx, fmaxf(fabsf(P0[c].x), fabsf(P0[c].y)));
            mx = fmaxf(mx, fmaxf(fabsf(P1[c].x), fabsf(P1[c].y)));
        }
        if (!__any(mx > 0.0f)) {
            uacc = (float)(L_DIM - 8 - i0) * NEG_HALF_LOG2;
            break;
        }
    }

    // Per-row sums: butterfly within each 8-lane group (xor 1,2,4).
    float s = vacc;
    s += __shfl_xor(s, 1, 64);
    s += __shfl_xor(s, 2, 64);
    s += __shfl_xor(s, 4, 64);
    if (lane == 0) out[b0] = s + uacc;
    if (lane == 8) out[b1] = s + uacc;
}

extern "C" void kernel_launch(void* const* d_in, const int* in_sizes, int n_in,
                              void* d_out, int out_size, void* d_ws, size_t ws_size,
                              hipStream_t stream) {
    const int*   indices = (const int*)d_in[0];
    const float* eps     = (const float*)d_in[1];
    float*       out     = (float*)d_out;

    const size_t need = (size_t)2 * N_DIM * L_DIM * sizeof(float);  // 4 MB
    if (ws_size >= need) {
        float* epsT = (float*)d_ws;
        dim3 tgrid(L_DIM / 32, N_DIM / 32, 2);
        transpose_eps<<<tgrid, dim3(32, 8), 0, stream>>>(eps, epsT);
        arqgps_main<true><<<B_DIM / 16, 512, 0, stream>>>(indices, eps, epsT, out);
    } else {
        arqgps_main<false><<<B_DIM / 16, 512, 0, stream>>>(indices, eps, nullptr, out);
    }
}